// Round 2
// baseline (161.825 us; speedup 1.0000x reference)
//
#include <hip/hip_runtime.h>

#define EG   16000   // graph edges
#define NG   1000    // graph_size (block rows/cols)
#define BB   32      // batch
#define SIZE 16000   // feature length (NG*16)
#define NNZ  (EG * 256)

// ---- prep: sample all weights once, coalesced stream (BW-bound) ----
__global__ __launch_bounds__(256) void prep_kernel(
    const float* __restrict__ wm, const float* __restrict__ wlv,
    const float* __restrict__ ew, float* __restrict__ v)
{
    int k = blockIdx.x * 256 + threadIdx.x;          // NNZ/4 = 1,024,000 lanes
    const float4 m = ((const float4*)wm)[k];
    const float4 l = ((const float4*)wlv)[k];
    const float4 e = ((const float4*)ew)[k];
    float4 r;
    r.x = fmaf(e.x, __expf(l.x), m.x);
    r.y = fmaf(e.y, __expf(l.y), m.y);
    r.z = fmaf(e.z, __expf(l.z), m.z);
    r.w = fmaf(e.w, __expf(l.w), m.w);
    ((float4*)v)[k] = r;
}

// ---- binning pipeline: bucket edges by destination block-row t0 ----
__global__ void count_kernel(const int* __restrict__ rows, int* __restrict__ cnt) {
    int e = blockIdx.x * blockDim.x + threadIdx.x;
    if (e < EG) {
        int t0 = rows[e << 8] >> 4;
        atomicAdd(&cnt[t0], 1);
    }
}

__global__ void scan_kernel(const int* __restrict__ cnt,
                            int* __restrict__ bin_start,
                            int* __restrict__ cursor) {
    __shared__ int s[1024];
    int t = threadIdx.x;
    int c = (t < NG) ? cnt[t] : 0;
    s[t] = c;
    __syncthreads();
    for (int off = 1; off < 1024; off <<= 1) {
        int v = (t >= off) ? s[t - off] : 0;
        __syncthreads();
        s[t] += v;
        __syncthreads();
    }
    int incl = s[t];
    if (t < NG) { bin_start[t] = incl - c; cursor[t] = incl - c; }
    if (t == 1023) bin_start[NG] = incl;
}

__global__ void scatter_kernel(const int* __restrict__ rows,
                               const int* __restrict__ cols,
                               int* __restrict__ cursor,
                               int* __restrict__ edge_of) {
    int e = blockIdx.x * blockDim.x + threadIdx.x;
    if (e < EG) {
        int t0 = rows[e << 8] >> 4;
        int t1 = cols[e << 8] >> 4;
        int pos = atomicAdd(&cursor[t0], 1);
        edge_of[pos] = e | (t1 << 16);       // pack: kills the cols hop in spmm
    }
}

// ---- main kernel: one 128-thread workgroup per destination block-row ----
// Thread t owns outputs (b0+8q, j) for q=0..3, j=t&15, b0=t>>4 (0..7).
// Per edge: 16 scalar weight-column loads (one 64B line each, broadcast) +
// 16 float4 x loads. No LDS in the loop, no barriers — iterations independent.
__global__ __launch_bounds__(128) void spmm_kernel(
    const float* __restrict__ v, const float* __restrict__ x,
    const float* __restrict__ bm, const float* __restrict__ blv,
    const float* __restrict__ eb, const int* __restrict__ edge_of,
    const int* __restrict__ bin_start, float* __restrict__ out)
{
    __shared__ int hdr[256];
    int g   = blockIdx.x;
    int tid = threadIdx.x;
    int j   = tid & 15;
    int b0  = tid >> 4;                       // 0..7

    int start = bin_start[g];
    int n     = bin_start[g + 1] - start;
    for (int t = tid; t < n && t < 256; t += 128) hdr[t] = edge_of[start + t];
    __syncthreads();

    float a0 = 0.f, a1 = 0.f, a2 = 0.f, a3 = 0.f;

    for (int p = 0; p < n; ++p) {
        int h  = (p < 256) ? hdr[p] : edge_of[start + p];
        int e  = h & 0xFFFF;
        int t1 = h >> 16;
        const float* wc = v + (e << 8) + j;   // column j of the 16x16 tile
        const float* xp = x + (t1 << 4);

        float4 X0[4], X1[4], X2[4], X3[4];
        #pragma unroll
        for (int q = 0; q < 4; ++q) {
            X0[q] = ((const float4*)(xp + (b0     ) * SIZE))[q];
            X1[q] = ((const float4*)(xp + (b0 +  8) * SIZE))[q];
            X2[q] = ((const float4*)(xp + (b0 + 16) * SIZE))[q];
            X3[q] = ((const float4*)(xp + (b0 + 24) * SIZE))[q];
        }
        float W[16];
        #pragma unroll
        for (int i = 0; i < 16; ++i) W[i] = wc[i << 4];

        const float* f0 = (const float*)X0;
        const float* f1 = (const float*)X1;
        const float* f2 = (const float*)X2;
        const float* f3 = (const float*)X3;
        #pragma unroll
        for (int i = 0; i < 16; ++i) {
            float wv = W[i];
            a0 = fmaf(wv, f0[i], a0);
            a1 = fmaf(wv, f1[i], a1);
            a2 = fmaf(wv, f2[i], a2);
            a3 = fmaf(wv, f3[i], a3);
        }
    }

    int r = (g << 4) + j;
    float bias = fmaf(eb[r], __expf(blv[r]), bm[r]);
    out[(b0     ) * SIZE + r] = a0 + bias;
    out[(b0 +  8) * SIZE + r] = a1 + bias;
    out[(b0 + 16) * SIZE + r] = a2 + bias;
    out[(b0 + 24) * SIZE + r] = a3 + bias;
    if (g == 0 && tid == 0) out[BB * SIZE] = 0.0f;   // kl scalar
}

extern "C" void kernel_launch(void* const* d_in, const int* in_sizes, int n_in,
                              void* d_out, int out_size, void* d_ws, size_t ws_size,
                              hipStream_t stream) {
    const float* x   = (const float*)d_in[0];
    const float* wm  = (const float*)d_in[1];
    const float* wlv = (const float*)d_in[2];
    const float* bm  = (const float*)d_in[3];
    const float* blv = (const float*)d_in[4];
    const float* ew  = (const float*)d_in[5];
    const float* eb  = (const float*)d_in[6];
    const int* rows  = (const int*)d_in[7];
    const int* cols  = (const int*)d_in[8];
    float* out = (float*)d_out;

    char* ws = (char*)d_ws;
    int*   cnt       = (int*)(ws);               // 1024 ints
    int*   bin_start = (int*)(ws + 4096);        // 1001 ints
    int*   cursor    = (int*)(ws + 8192);        // 1000 ints
    int*   edge_of   = (int*)(ws + 12288);       // 16000 ints
    float* v         = (float*)(ws + 131072);    // NNZ floats (16.4 MB)

    hipMemsetAsync(cnt, 0, 4096, stream);
    prep_kernel<<<NNZ / 4 / 256, 256, 0, stream>>>(wm, wlv, ew, v);
    count_kernel<<<(EG + 255) / 256, 256, 0, stream>>>(rows, cnt);
    scan_kernel<<<1, 1024, 0, stream>>>(cnt, bin_start, cursor);
    scatter_kernel<<<(EG + 255) / 256, 256, 0, stream>>>(rows, cols, cursor, edge_of);
    spmm_kernel<<<NG, 128, 0, stream>>>(v, x, bm, blv, eb, edge_of, bin_start, out);
}